// Round 5
// baseline (485.426 us; speedup 1.0000x reference)
//
#include <hip/hip_runtime.h>
#include <hip/hip_fp16.h>
#include <cstdint>
#include <cstddef>

typedef unsigned long long u64;
typedef unsigned int u32;
typedef __attribute__((ext_vector_type(8))) _Float16 f16x8;
typedef __attribute__((ext_vector_type(4))) float f32x4;

#define NANCHORS 39375
#define PRE_NMS  2000
#define POST_NMS 300
#define CAND_CAP 4096
#define MPAD 2048          // padded row count of mask matrix
#define UNEG 0x007FFFFFu   // f2u(-inf)

__device__ __forceinline__ u32 f2u(float f) {
  u32 u = __float_as_uint(f);
  return (u & 0x80000000u) ? ~u : (u | 0x80000000u);
}

// async global->LDS, 16B per lane. LDS dest must be WAVE-UNIFORM base; HW adds lane*16.
#define GLOAD16(gp, lp) __builtin_amdgcn_global_load_lds( \
    (const __attribute__((address_space(1))) u32*)(const void*)(gp), \
    (__attribute__((address_space(3))) u32*)(void*)(lp), 16, 0, 0)

// ---------------- input split/transpose: NCHW f32 -> padded channels-last fp16 hi/lo ----
__global__ __launch_bounds__(256) void xsplit_kernel(
    const float* __restrict__ f0, const float* __restrict__ f1, const float* __restrict__ f2,
    short* __restrict__ xh, short* __restrict__ xl)
{
  __shared__ float tile[64][65];
  int t = blockIdx.x;
  int HW, W, W2, np; const float* fp; int AB, ABS;
  if (t < 1256)      { HW = 10000; W = 100; W2 = 102; np = 157; fp = f0; AB = 0;       ABS = 2663424; }
  else if (t < 1576) { t -= 1256; HW = 2500; W = 50; W2 = 52; np = 40; fp = f1; AB = 5326848; ABS = 692224; }
  else               { t -= 1576; HW = 625;  W = 25; W2 = 27; np = 10; fp = f2; AB = 6711296; ABS = 186624; }
  int posb = t % np, r = t / np;
  int ci0 = (r & 3) * 64, b = r >> 2;
  int pos0 = posb * 64;
  int tid = threadIdx.x, lane = tid & 63, w = tid >> 6;
  int rp = pos0 + lane; if (rp >= HW) rp = HW - 1;
  const float* src = fp + (size_t)(b * 256 + ci0) * HW;
#pragma unroll
  for (int p = 0; p < 16; ++p) {
    int cl = w * 16 + p;
    tile[cl][lane] = src[(size_t)cl * HW + rp];
  }
  __syncthreads();
  int pix = tid >> 2, cq = tid & 3;
  int pos = pos0 + pix;
  if (pos < HW) {
    int y = pos / W, x = pos - y * W;
    size_t ob = (size_t)AB + (size_t)b * ABS + ((size_t)((y + 1) * W2 + (x + 1))) * 256 + ci0 + cq * 16;
    __align__(16) short hs[16], ls[16];
#pragma unroll
    for (int j = 0; j < 16; ++j) {
      float v = tile[cq * 16 + j][pix];
      __half h = __float2half(v);
      __half l = __float2half((v - __half2float(h)) * 2048.0f);
      hs[j] = __half_as_short(h);
      ls[j] = __half_as_short(l);
    }
    *(int4*)(xh + ob) = ((int4*)hs)[0];
    *(int4*)(xh + ob + 8) = ((int4*)hs)[1];
    *(int4*)(xl + ob) = ((int4*)ls)[0];
    *(int4*)(xl + ob + 8) = ((int4*)ls)[1];
  }
}

// ---------------- weight split: [co][ci][tap] f32 -> B^T layout [tap][co][ci] fp16 hi/lo --
__global__ __launch_bounds__(256) void wsplit_kernel(
    const float* __restrict__ w, short* __restrict__ wh, short* __restrict__ wl)
{
  int idx = blockIdx.x * 256 + threadIdx.x;    // < 589824 = 9*256*256 exactly
  int tap = idx >> 16, co = (idx >> 8) & 255, ci = idx & 255;
  float v = w[(size_t)co * 2304 + ci * 9 + tap];
  __half h = __float2half(v);
  __half l = __float2half((v - __half2float(h)) * 2048.0f);
  wh[idx] = __half_as_short(h);
  wl[idx] = __half_as_short(l);
}

// ---------------- conv 3x3 as implicit-GEMM on MFMA (split-fp16, error-compensated) -----
// v2: 8 waves (512 thr), 128x128 tile; A-fragments loaded DIRECT from global (contiguous
// 16B runs in padded channels-last layout, L1-served: per-chunk A slice = 32KB); only B
// staged in LDS (32KB, XOR-swizzled). Waves/SIMD 1.6 -> 3.2 to feed the MFMA pipe.
__global__ __launch_bounds__(512, 2) void gemmconv_kernel(
    const short* __restrict__ xh, const short* __restrict__ xl,
    const short* __restrict__ wh, const short* __restrict__ wl,
    const float* __restrict__ bias, float* __restrict__ hbase)
{
  __shared__ __align__(16) short smem[16384];  // Bh[128][64] | Bl[128][64]

  int lb = (blockIdx.x & 7) * 52 + (blockIdx.x >> 3);
  int HW, W, W2, AB, ABS; size_t hoff;
  if (lb < 316)      { HW = 10000; W = 100; W2 = 102; AB = 0;       ABS = 2663424; hoff = 0; }
  else if (lb < 396) { lb -= 316; HW = 2500; W = 50; W2 = 52; AB = 5326848; ABS = 692224; hoff = 5120000; }
  else               { lb -= 396; HW = 625;  W = 25; W2 = 27; AB = 6711296; ABS = 186624; hoff = 6400000; }
  int mb = lb >> 2, b = (lb >> 1) & 1, nb = lb & 1;
  int pos0 = mb * 128, co0 = nb * 128;

  int tid = threadIdx.x;
  // B staging: 2 passes of 64 rows; thread t -> row t>>3, 16B slot t&7 (XOR-swizzled col)
  int brow = tid >> 3, s = tid & 7;
  int boff0 = ((co0 + brow) << 8) + ((s ^ (brow & 7)) << 3);
  int boff1 = ((co0 + 64 + brow) << 8) + ((s ^ ((64 + brow) & 7)) << 3);

  int wv = tid >> 6, lane = tid & 63;
  int lr = lane & 15, lk = lane >> 4;
  int wr = wv >> 1, wc = wv & 1;               // wr 0..3 (32-row bands), wc 0..1 (64-co)
  int rB0 = wc * 64 + lr;
  int cs = (lr & 7) << 4;
  int c0 = ((lk * 16) ^ cs) >> 1;              // short offset, k2=0
  int c1 = ((64 + lk * 16) ^ cs) >> 1;         // short offset, k2=1

  // A direct-global per-lane bases (row = pos0 + wr*32 + q*16 + lr; tail rows clamped)
  int abase[2];
#pragma unroll
  for (int q = 0; q < 2; ++q) {
    int pos = pos0 + wr * 32 + q * 16 + lr;
    if (pos >= HW) pos = HW - 1;
    int y = pos / W, x = pos - y * W;
    abase[q] = AB + b * ABS + (y * W2 + x) * 256 + lk * 8;
  }

  f32x4 acc1[2][4], acc2[2][4];
  f32x4 zro = {0.f, 0.f, 0.f, 0.f};
#pragma unroll
  for (int q = 0; q < 2; ++q)
#pragma unroll
    for (int j = 0; j < 4; ++j) { acc1[q][j] = zro; acc2[q][j] = zro; }

  for (int cc = 0; cc < 36; ++cc) {
    int tap = cc >> 2, cq = cc & 3;
    int ty = tap / 3, tx = tap - ty * 3;
    int adel = (ty * W2 + tx) * 256 + (cq << 6);
    int bdel = (tap << 16) + (cq << 6);
    if (cc) __syncthreads();                   // protect LDS overwrite
    GLOAD16(wh + boff0 + bdel, smem + (wv << 9));
    GLOAD16(wh + boff1 + bdel, smem + 4096 + (wv << 9));
    GLOAD16(wl + boff0 + bdel, smem + 8192 + (wv << 9));
    GLOAD16(wl + boff1 + bdel, smem + 12288 + (wv << 9));
    __syncthreads();                           // drains vmcnt before barrier
#pragma unroll
    for (int k2 = 0; k2 < 2; ++k2) {
      int ck = k2 ? c1 : c0;
      f16x8 ah[2], al[2], bh[4], bl[4];
#pragma unroll
      for (int q = 0; q < 2; ++q) {
        ah[q] = *(const f16x8*)(xh + abase[q] + adel + k2 * 32);
        al[q] = *(const f16x8*)(xl + abase[q] + adel + k2 * 32);
      }
#pragma unroll
      for (int n4 = 0; n4 < 4; ++n4) {
        int rb = (rB0 + n4 * 16) * 64 + ck;
        bh[n4] = *(const f16x8*)(smem + rb);
        bl[n4] = *(const f16x8*)(smem + 8192 + rb);
      }
#pragma unroll
      for (int q = 0; q < 2; ++q)
#pragma unroll
        for (int n4 = 0; n4 < 4; ++n4) {
          acc1[q][n4] = __builtin_amdgcn_mfma_f32_16x16x32_f16(ah[q], bh[n4], acc1[q][n4], 0, 0, 0);
          acc2[q][n4] = __builtin_amdgcn_mfma_f32_16x16x32_f16(ah[q], bl[n4], acc2[q][n4], 0, 0, 0);
          acc2[q][n4] = __builtin_amdgcn_mfma_f32_16x16x32_f16(al[q], bh[n4], acc2[q][n4], 0, 0, 0);
        }
    }
  }

  float br[4];
#pragma unroll
  for (int n4 = 0; n4 < 4; ++n4) br[n4] = bias[co0 + wc * 64 + n4 * 16 + lr];
  float* outb = hbase + hoff + (size_t)b * HW * 256;
#pragma unroll
  for (int q = 0; q < 2; ++q) {
#pragma unroll
    for (int j = 0; j < 4; ++j) {
      int pos = pos0 + wr * 32 + q * 16 + lk * 4 + j;  // C: row=(lane>>4)*4+reg, col=lane&15
      if (pos < HW) {
        float* op = outb + (size_t)pos * 256 + co0 + wc * 64 + lr;
#pragma unroll
        for (int n4 = 0; n4 < 4; ++n4)
          op[n4 * 16] = acc1[q][n4][j] + acc2[q][n4][j] * 4.8828125e-4f + br[n4];
      }
    }
  }
}

// ---------------- heads v2: 4 threads/pixel, LDS-staged transposed weights, f32 VALU ----
// Block = 256 thr = 64 px. wT[q][64][20] f32 with per-q pad 8 words -> the four q-groups'
// ds_read_b128 land on banks {0,8,16,24}: conflict-free. Per thread: 16 coalesced-ish
// float4 h-loads (L1-amortized), 320 ds_read_b128, 1280 FMA; 2-step shfl_xor reduce.
__global__ __launch_bounds__(256) void head_kernel(
    const float* __restrict__ hbase, const float* __restrict__ loc_w, const float* __restrict__ loc_b,
    const float* __restrict__ score_w, const float* __restrict__ score_b,
    const float* __restrict__ anchors, const int* __restrict__ imgh, const int* __restrict__ imgw,
    float* __restrict__ out_locs, float* __restrict__ out_scores,
    float* __restrict__ boxes, u32* __restrict__ ukey)
{
  __shared__ float wT[4 * 1288];
  int tid = threadIdx.x;
  for (int idx = tid; idx < 4608; idx += 256) {          // 18*256
    int o = idx >> 8, c = idx & 255;
    float v = (o < 12) ? loc_w[o * 256 + c] : score_w[(o - 12) * 256 + c];
    wT[(c >> 6) * 1288 + (c & 63) * 20 + o] = v;
  }
  for (int idx = tid; idx < 512; idx += 256) {           // zero pad outputs 18,19
    int c = idx >> 1, o = 18 + (idx & 1);
    wT[(c >> 6) * 1288 + (c & 63) * 20 + o] = 0.f;
  }
  __syncthreads();

  int t = blockIdx.x;
  int b = t / 207, r = t % 207;
  int HW, pos0, base_row; size_t hoff;
  if (r < 157)      { HW = 10000; pos0 = r * 64;         base_row = 0;     hoff = 0; }
  else if (r < 197) { HW = 2500;  pos0 = (r - 157) * 64; base_row = 30000; hoff = 5120000; }
  else              { HW = 625;   pos0 = (r - 197) * 64; base_row = 37500; hoff = 6400000; }

  int px = tid >> 2, q = tid & 3;
  int pos = pos0 + px;
  int pc = (pos < HW) ? pos : HW - 1;
  const float* hp = hbase + hoff + ((size_t)b * HW + pc) * 256 + q * 64;
  const float* wq = wT + q * 1288;

  f32x4 acc[5];
#pragma unroll
  for (int o4 = 0; o4 < 5; ++o4) acc[o4] = (f32x4){0.f, 0.f, 0.f, 0.f};

#pragma unroll 4
  for (int i = 0; i < 16; ++i) {
    float4 hv = *(const float4*)(hp + i * 4);
    float hk[4] = {fmaxf(hv.x, 0.f), fmaxf(hv.y, 0.f), fmaxf(hv.z, 0.f), fmaxf(hv.w, 0.f)};
#pragma unroll
    for (int k = 0; k < 4; ++k) {
      const float4* wrow = (const float4*)(wq + (i * 4 + k) * 20);
#pragma unroll
      for (int o4 = 0; o4 < 5; ++o4) {
        float4 wv = wrow[o4];
        acc[o4][0] = fmaf(hk[k], wv.x, acc[o4][0]);
        acc[o4][1] = fmaf(hk[k], wv.y, acc[o4][1]);
        acc[o4][2] = fmaf(hk[k], wv.z, acc[o4][2]);
        acc[o4][3] = fmaf(hk[k], wv.w, acc[o4][3]);
      }
    }
  }
  // reduce over q (4-lane groups)
#pragma unroll
  for (int o4 = 0; o4 < 5; ++o4)
#pragma unroll
    for (int cpo = 0; cpo < 4; ++cpo) {
      float v = acc[o4][cpo];
      v += __shfl_xor(v, 1, 64);
      v += __shfl_xor(v, 2, 64);
      acc[o4][cpo] = v;
    }

  if (q == 0 && pos < HW) {
    float sarr[18] = {acc[0][0], acc[0][1], acc[0][2], acc[0][3],
                      acc[1][0], acc[1][1], acc[1][2], acc[1][3],
                      acc[2][0], acc[2][1], acc[2][2], acc[2][3],
                      acc[3][0], acc[3][1], acc[3][2], acc[3][3],
                      acc[4][0], acc[4][1]};
    float IH = (float)(*imgh), IW = (float)(*imgw);
#pragma unroll
    for (int a = 0; a < 3; ++a) {
      float l0 = sarr[4 * a + 0] + loc_b[4 * a + 0];
      float l1 = sarr[4 * a + 1] + loc_b[4 * a + 1];
      float l2 = sarr[4 * a + 2] + loc_b[4 * a + 2];
      float l3 = sarr[4 * a + 3] + loc_b[4 * a + 3];
      float sc0 = sarr[12 + 2 * a + 0] + score_b[2 * a + 0];
      float sc1 = sarr[12 + 2 * a + 1] + score_b[2 * a + 1];

      int row = base_row + pos * 3 + a;
      size_t g = (size_t)b * NANCHORS + row;
      *(float4*)(out_locs + g * 4) = make_float4(l0, l1, l2, l3);
      out_scores[g * 2 + 0] = sc0; out_scores[g * 2 + 1] = sc1;

      float mx = fmaxf(sc0, sc1);
      float e0 = expf(sc0 - mx), e1 = expf(sc1 - mx);
      float fg = e1 / (e0 + e1);

      const float* an = anchors + (size_t)row * 4;
      float a0 = an[0], a1 = an[1], a2 = an[2], a3 = an[3];
      float sh = a2 - a0, sw = a3 - a1;
      float cy = a0 + 0.5f * sh, cx = a1 + 0.5f * sw;
      float ncy = l0 * sh + cy, ncx = l1 * sw + cx;
      float nh = expf(l2) * sh, nw = expf(l3) * sw;
      float y1 = fminf(fmaxf(ncy - 0.5f * nh, 0.f), IH);
      float x1 = fminf(fmaxf(ncx - 0.5f * nw, 0.f), IW);
      float y2 = fminf(fmaxf(ncy + 0.5f * nh, 0.f), IH);
      float x2 = fminf(fmaxf(ncx + 0.5f * nw, 0.f), IW);
      bool valid = ((y2 - y1) >= 16.0f) && ((x2 - x1) >= 16.0f);
      float scm = valid ? fg : -__builtin_inff();

      *(float4*)(boxes + g * 4) = make_float4(y1, x1, y2, x2);
      ukey[g] = f2u(scm);
    }
  }
}

// ---------------- copy anchors to output ----------------
__global__ void copyf_kernel(const float* __restrict__ a, float* __restrict__ o, int n) {
  int t = blockIdx.x * 256 + threadIdx.x;
  if (t < n) o[t] = a[t];
}

// ---------------- merged radix-select + bitonic sort (same 2x1024 grid) -----------------
// select compacts candidates straight into shared key[]; sort runs in-place; emits topbox
// + initial suppressed mask. cand global buffer eliminated.
__global__ __launch_bounds__(1024) void selectsort_kernel(
    const u32* __restrict__ ukey, const float* __restrict__ boxes,
    float* __restrict__ topbox, u64* __restrict__ sup0)
{
  int b = blockIdx.x, tid = threadIdx.x;
  int wv = tid >> 6;
  const u32* u = ukey + (size_t)b * NANCHORS;
  __shared__ u32 hist[16][256];
  __shared__ u32 scan[256];
  __shared__ u32 sh_prefix;
  __shared__ int sh_rem;
  __shared__ int sh_cnt;
  __shared__ u64 key[CAND_CAP];
  __shared__ unsigned char validf[2048];

  u32 prefix = 0; int rem = PRE_NMS;
  for (int pass = 0; pass < 4; ++pass) {
    int shift = 24 - 8 * pass;
    for (int i = tid; i < 16 * 256; i += 1024) ((u32*)hist)[i] = 0;
    __syncthreads();
    u32 himask = (pass == 0) ? 0u : (0xFFFFFFFFu << (shift + 8));
    for (int i = tid; i < NANCHORS; i += 1024) {
      u32 v = u[i];
      if ((v & himask) == (prefix & himask))
        atomicAdd(&hist[wv][(v >> shift) & 255u], 1u);
    }
    __syncthreads();
    if (tid < 256) {
      u32 s = 0;
#pragma unroll
      for (int k = 0; k < 16; ++k) s += hist[k][tid];
      scan[tid] = s;
    }
    __syncthreads();
    for (int off = 1; off < 256; off <<= 1) {
      u32 v = 0, add = 0;
      if (tid < 256) { v = scan[tid]; if (tid + off < 256) add = scan[tid + off]; }
      __syncthreads();
      if (tid < 256) scan[tid] = v + add;
      __syncthreads();
    }
    if (tid < 256) {
      int s = (int)scan[tid];
      int snext = (tid < 255) ? (int)scan[tid + 1] : 0;
      if (s >= rem && snext < rem) { sh_prefix = prefix | ((u32)tid << shift); sh_rem = rem - snext; }
    }
    __syncthreads();
    prefix = sh_prefix; rem = sh_rem;
    __syncthreads();
  }

  if (tid == 0) sh_cnt = 0;
  __syncthreads();
  for (int i = tid; i < NANCHORS; i += 1024) {
    u32 v = u[i];
    if (v >= prefix) {
      int p = atomicAdd(&sh_cnt, 1);
      if (p < CAND_CAP)
        key[p] = ((u64)v << 32) | (u32)(~(u32)i);
    }
  }
  __syncthreads();
  int cnt = (sh_cnt < CAND_CAP) ? sh_cnt : CAND_CAP;
  for (int t = tid; t < CAND_CAP; t += 1024)
    if (t >= cnt) key[t] = 0ull;
  __syncthreads();

  u32 n = (cnt <= 2048) ? 2048u : (u32)CAND_CAP;
  for (u32 k = 2; k <= n; k <<= 1) {
    for (u32 j = k >> 1; j > 0; j >>= 1) {
      __syncthreads();
      for (u32 t = tid; t < n; t += 1024) {
        u32 ixj = t ^ j;
        if (ixj > t) {
          u64 a = key[t], c = key[ixj];
          bool desc = ((t & k) == 0);
          if (desc ? (a < c) : (a > c)) { key[t] = c; key[ixj] = a; }
        }
      }
    }
  }
  __syncthreads();

  for (int t = tid; t < 2048; t += 1024) {
    unsigned char vf = 0;
    if (t < PRE_NMS) {
      u64 kk = key[t];
      u32 uu = (u32)(kk >> 32);
      float* tb = topbox + ((size_t)b * PRE_NMS + t) * 4;
      if (uu != 0u) {
        u32 idx = ~((u32)kk);
        const float* bp = boxes + ((size_t)b * NANCHORS + idx) * 4;
        tb[0] = bp[0]; tb[1] = bp[1]; tb[2] = bp[2]; tb[3] = bp[3];
        vf = (uu != UNEG) ? 1 : 0;
      } else {
        tb[0] = 0.f; tb[1] = 0.f; tb[2] = 0.f; tb[3] = 0.f;
      }
    }
    validf[t] = vf;
  }
  __syncthreads();
  if (tid < 32) {
    u64 m = 0;
    for (int bit = 0; bit < 64; ++bit) {
      int j = tid * 64 + bit;
      if (j >= PRE_NMS || !validf[j]) m |= (1ull << bit);
    }
    sup0[b * 32 + tid] = m;
  }
}

// ---------------- pairwise IoU suppression bitmask, TRANSPOSED u32 layout ---------------
__global__ __launch_bounds__(256) void iou_kernel(const float* __restrict__ topbox, u32* __restrict__ M32)
{
  int t = blockIdx.x * 256 + threadIdx.x;   // < 64000
  int b = blockIdx.y;
  int w = t / 2000, i = t % 2000;
  const float* tb = topbox + (size_t)b * PRE_NMS * 4;
  const float* bi = tb + (size_t)i * 4;
  float iy1 = bi[0], ix1 = bi[1], iy2 = bi[2], ix2 = bi[3];
  float ai = (iy2 - iy1) * (ix2 - ix1);
  u64 m = 0;
  for (int bit = 0; bit < 64; ++bit) {
    int j = w * 64 + bit;
    if (j < PRE_NMS && j > i) {
      const float* bj = tb + (size_t)j * 4;
      float ty = fmaxf(iy1, bj[0]), tx = fmaxf(ix1, bj[1]);
      float by = fminf(iy2, bj[2]), bx = fminf(ix2, bj[3]);
      float hh = fmaxf(by - ty, 0.f), ww = fmaxf(bx - tx, 0.f);
      float inter = hh * ww;
      float aj = (bj[2] - bj[0]) * (bj[3] - bj[1]);
      float iou = inter / (ai + aj - inter + 1e-12f);
      if (iou > 0.7f) m |= (1ull << bit);
    }
  }
  u32* out = M32 + (size_t)b * MPAD * 64;
  out[(size_t)(2 * w)     * MPAD + i] = (u32)m;
  out[(size_t)(2 * w + 1) * MPAD + i] = (u32)(m >> 32);
}

// ---------------- merged NMS scan (1 wave, distributed regs) + emit top-300 -------------
__global__ __launch_bounds__(320) void final_kernel(
    const u32* __restrict__ M32, const u64* __restrict__ sup0, const float* __restrict__ topbox,
    float* __restrict__ rois, float* __restrict__ roiidx)
{
  int b = blockIdx.x, tid = threadIdx.x;
  __shared__ u32 supl[64];
  __shared__ int ord[POST_NMS];
  __shared__ int cnt_s;

  if (tid < 64) {
    int l = tid;                            // lane l owns u32 word l
    const u32* col = M32 + (size_t)b * MPAD * 64 + (size_t)l * MPAD;
    u32 sup = ((const u32*)sup0)[b * 64 + l];
    uint4 A[16], B[16];
#pragma unroll
    for (int k = 0; k < 16; ++k) A[k] = *(const uint4*)(col + 4 * k);

#define NMS_PROC(buf, cc) do {                                                     \
  _Pragma("unroll")                                                                \
  for (int rr = 0; rr < 64; ++rr) {                                                \
    u32 d = ((rr & 3) == 0) ? buf[rr >> 2].x : ((rr & 3) == 1) ? buf[rr >> 2].y :  \
            ((rr & 3) == 2) ? buf[rr >> 2].z : buf[rr >> 2].w;                     \
    u32 sb = (u32)__builtin_amdgcn_readlane((int)sup, 2 * (cc) + (rr >> 5));       \
    u32 m = ((sb >> (rr & 31)) & 1u) - 1u;                                         \
    sup |= m & d;                                                                  \
  } } while (0)

    for (int c = 0; c < 32; c += 2) {
#pragma unroll
      for (int k = 0; k < 16; ++k) B[k] = *(const uint4*)(col + (c + 1) * 64 + 4 * k);
      NMS_PROC(A, c);
      if (c + 2 < 32) {
#pragma unroll
        for (int k = 0; k < 16; ++k) A[k] = *(const uint4*)(col + (c + 2) * 64 + 4 * k);
      }
      NMS_PROC(B, c + 1);
    }
    supl[l] = sup;
  }
  __syncthreads();
  if (tid == 0) {
    int cnt = 0;
    for (int w = 0; w < 64 && cnt < POST_NMS; ++w) {
      u32 kept = ~supl[w];
      while (kept && cnt < POST_NMS) {
        int bit = __builtin_ctz(kept); kept &= kept - 1;
        ord[cnt++] = w * 32 + bit;
      }
    }
    cnt_s = cnt;
  }
  __syncthreads();
  if (tid < POST_NMS) {
    float v0 = 0.f, v1 = 0.f, v2 = 0.f, v3 = 0.f;
    if (tid < cnt_s) {
      const float* tb = topbox + ((size_t)b * PRE_NMS + ord[tid]) * 4;
      v0 = tb[0]; v1 = tb[1]; v2 = tb[2]; v3 = tb[3];
    }
    float* r = rois + ((size_t)b * POST_NMS + tid) * 4;
    r[0] = v0; r[1] = v1; r[2] = v2; r[3] = v3;
    roiidx[b * POST_NMS + tid] = (float)b;
  }
}

extern "C" void kernel_launch(void* const* d_in, const int* in_sizes, int n_in,
                              void* d_out, int out_size, void* d_ws, size_t ws_size,
                              hipStream_t stream) {
  const float* feat0   = (const float*)d_in[0];
  const float* feat1   = (const float*)d_in[1];
  const float* feat2   = (const float*)d_in[2];
  const float* conv_w  = (const float*)d_in[3];
  const float* conv_b  = (const float*)d_in[4];
  const float* score_w = (const float*)d_in[5];
  const float* score_b = (const float*)d_in[6];
  const float* loc_w   = (const float*)d_in[7];
  const float* loc_b   = (const float*)d_in[8];
  const float* anchors = (const float*)d_in[9];
  const int*   img_h   = (const int*)d_in[10];
  const int*   img_w   = (const int*)d_in[11];

  float* out_f       = (float*)d_out;
  float* out_locs    = out_f;                // 2*39375*4
  float* out_scores  = out_f + 315000;       // 2*39375*2
  float* out_rois    = out_f + 472500;       // 600*4
  float* out_roiidx  = out_f + 474900;       // 600
  float* out_anchors = out_f + 475500;       // 39375*4

  char* p = (char*)d_ws;
  float* hb = (float*)p;      p += (size_t)6720000 * 4;   // h = conv+bias (channels-last)
  short* xth = (short*)p;     p += (size_t)7084544 * 2;   // padded channels-last fp16 hi
  short* xtl = (short*)p;     p += (size_t)7084544 * 2;   // fp16 lo * 2^11
  short* wsh = (short*)p;     p += (size_t)589824 * 2;    // weights B^T [tap][co][ci] hi
  short* wsl = (short*)p;     p += (size_t)589824 * 2;    // lo * 2^11
  float* boxes = (float*)p;   p += (size_t)315000 * 4;    // 2*39375*4
  u32* ukey = (u32*)p;        p += (size_t)78752 * 4;     // 2*39375 (+2 pad: 16B align)
  float* topbox = (float*)p;  p += (size_t)16000 * 4;     // 2*2000*4
  u32* M32 = (u32*)p;         p += (size_t)2 * MPAD * 64 * 4;  // transposed mask
  u64* sup0 = (u64*)p;        p += 64 * 8;

  // zero the spatial pad ring of xth+xtl (adjacent: one memset)
  hipMemsetAsync(xth, 0, (size_t)7084544 * 4, stream);
  xsplit_kernel<<<1656, 256, 0, stream>>>(feat0, feat1, feat2, xth, xtl);
  wsplit_kernel<<<2304, 256, 0, stream>>>(conv_w, wsh, wsl);
  gemmconv_kernel<<<416, 512, 0, stream>>>(xth, xtl, wsh, wsl, conv_b, hb);
  head_kernel<<<414, 256, 0, stream>>>(
      hb, loc_w, loc_b, score_w, score_b, anchors, img_h, img_w,
      out_locs, out_scores, boxes, ukey);
  copyf_kernel<<<(157500 + 255) / 256, 256, 0, stream>>>(anchors, out_anchors, 157500);
  selectsort_kernel<<<2, 1024, 0, stream>>>(ukey, boxes, topbox, sup0);
  iou_kernel<<<dim3(250, 2), 256, 0, stream>>>(topbox, M32);
  final_kernel<<<2, 320, 0, stream>>>(M32, sup0, topbox, out_rois, out_roiidx);
}

// Round 6
// 370.715 us; speedup vs baseline: 1.3094x; 1.3094x over previous
//
#include <hip/hip_runtime.h>
#include <hip/hip_fp16.h>
#include <cstdint>
#include <cstddef>

typedef unsigned long long u64;
typedef unsigned int u32;
typedef __attribute__((ext_vector_type(8))) _Float16 f16x8;
typedef __attribute__((ext_vector_type(4))) float f32x4;

#define NANCHORS 39375
#define PRE_NMS  2000
#define POST_NMS 300
#define CAND_CAP 4096
#define MPAD 2048          // padded row count of mask matrix
#define UNEG 0x007FFFFFu   // f2u(-inf)

__device__ __forceinline__ u32 f2u(float f) {
  u32 u = __float_as_uint(f);
  return (u & 0x80000000u) ? ~u : (u | 0x80000000u);
}

// async global->LDS, 16B per lane. LDS dest must be WAVE-UNIFORM base; HW adds lane*16.
#define GLOAD16(gp, lp) __builtin_amdgcn_global_load_lds( \
    (const __attribute__((address_space(1))) u32*)(const void*)(gp), \
    (__attribute__((address_space(3))) u32*)(void*)(lp), 16, 0, 0)

// ---------------- input split/transpose: NCHW f32 -> padded channels-last fp16 hi/lo ----
__global__ __launch_bounds__(256) void xsplit_kernel(
    const float* __restrict__ f0, const float* __restrict__ f1, const float* __restrict__ f2,
    short* __restrict__ xh, short* __restrict__ xl)
{
  __shared__ float tile[64][65];
  int t = blockIdx.x;
  int HW, W, W2, np; const float* fp; int AB, ABS;
  if (t < 1256)      { HW = 10000; W = 100; W2 = 102; np = 157; fp = f0; AB = 0;       ABS = 2663424; }
  else if (t < 1576) { t -= 1256; HW = 2500; W = 50; W2 = 52; np = 40; fp = f1; AB = 5326848; ABS = 692224; }
  else               { t -= 1576; HW = 625;  W = 25; W2 = 27; np = 10; fp = f2; AB = 6711296; ABS = 186624; }
  int posb = t % np, r = t / np;
  int ci0 = (r & 3) * 64, b = r >> 2;
  int pos0 = posb * 64;
  int tid = threadIdx.x, lane = tid & 63, w = tid >> 6;
  int rp = pos0 + lane; if (rp >= HW) rp = HW - 1;
  const float* src = fp + (size_t)(b * 256 + ci0) * HW;
#pragma unroll
  for (int p = 0; p < 16; ++p) {
    int cl = w * 16 + p;
    tile[cl][lane] = src[(size_t)cl * HW + rp];
  }
  __syncthreads();
  int pix = tid >> 2, cq = tid & 3;
  int pos = pos0 + pix;
  if (pos < HW) {
    int y = pos / W, x = pos - y * W;
    size_t ob = (size_t)AB + (size_t)b * ABS + ((size_t)((y + 1) * W2 + (x + 1))) * 256 + ci0 + cq * 16;
    __align__(16) short hs[16], ls[16];
#pragma unroll
    for (int j = 0; j < 16; ++j) {
      float v = tile[cq * 16 + j][pix];
      __half h = __float2half(v);
      __half l = __float2half((v - __half2float(h)) * 2048.0f);
      hs[j] = __half_as_short(h);
      ls[j] = __half_as_short(l);
    }
    *(int4*)(xh + ob) = ((int4*)hs)[0];
    *(int4*)(xh + ob + 8) = ((int4*)hs)[1];
    *(int4*)(xl + ob) = ((int4*)ls)[0];
    *(int4*)(xl + ob + 8) = ((int4*)ls)[1];
  }
}

// ---------------- weight split: [co][ci][tap] f32 -> B^T layout [tap][co][ci] fp16 hi/lo --
__global__ __launch_bounds__(256) void wsplit_kernel(
    const float* __restrict__ w, short* __restrict__ wh, short* __restrict__ wl)
{
  int idx = blockIdx.x * 256 + threadIdx.x;    // < 589824 = 9*256*256 exactly
  int tap = idx >> 16, co = (idx >> 8) & 255, ci = idx & 255;
  float v = w[(size_t)co * 2304 + ci * 9 + tap];
  __half h = __float2half(v);
  __half l = __float2half((v - __half2float(h)) * 2048.0f);
  wh[idx] = __half_as_short(h);
  wl[idx] = __half_as_short(l);
}

// ---------------- conv 3x3 as implicit-GEMM on MFMA (split-fp16, error-compensated) -----
// R4-proven version: 256 thr / 4 waves, 128x128 tile, A+B both LDS-staged (64KB), XOR
// swizzle both sides. LDS-read-pipe-bound at MfmaUtil ~45% (8 waves/CU x 32 b128/chunk
// = 2048 LDS-cyc vs 920 MFMA-cyc). Do NOT replace LDS-A with direct-global A: lane-
// scattered 512B-stride gathers thrash L1 (R5: 206us, MfmaUtil 18%).
__global__ __launch_bounds__(256, 2) void gemmconv_kernel(
    const short* __restrict__ xh, const short* __restrict__ xl,
    const short* __restrict__ wh, const short* __restrict__ wl,
    const float* __restrict__ bias, float* __restrict__ hbase)
{
  __shared__ __align__(16) short smem[32768];  // Ah[128][64] | Al | Bh[128][64] | Bl

  int lb = (blockIdx.x & 7) * 52 + (blockIdx.x >> 3);
  int HW, W, W2, AB, ABS; size_t hoff;
  if (lb < 316)      { HW = 10000; W = 100; W2 = 102; AB = 0;       ABS = 2663424; hoff = 0; }
  else if (lb < 396) { lb -= 316; HW = 2500; W = 50; W2 = 52; AB = 5326848; ABS = 692224; hoff = 5120000; }
  else               { lb -= 396; HW = 625;  W = 25; W2 = 27; AB = 6711296; ABS = 186624; hoff = 6400000; }
  int mb = lb >> 2, b = (lb >> 1) & 1, nb = lb & 1;
  int pos0 = mb * 128, co0 = nb * 128;

  int tid = threadIdx.x;
  int s = tid & 7, mrow = tid >> 3;
  int aoff[4], boff[4];
#pragma unroll
  for (int i = 0; i < 4; ++i) {
    int m = i * 32 + mrow;
    int pos = pos0 + m; if (pos >= HW) pos = HW - 1;   // tail rows: clamp (store is masked)
    int y = pos / W, x = pos - y * W;
    aoff[i] = AB + b * ABS + (y * W2 + x) * 256 + ((s ^ (m & 7)) << 3);
    boff[i] = ((co0 + m) << 8) + ((s ^ (m & 7)) << 3);
  }
  int wv = tid >> 6, lane = tid & 63;
  int lr = lane & 15, lk = lane >> 4;
  int wr = wv >> 1, wc = wv & 1;
  int rA0 = wr * 64 + lr, rB0 = wc * 64 + lr;
  int cs = (lr & 7) << 4;
  int c0 = ((lk * 16) ^ cs) >> 1;
  int c1 = ((64 + lk * 16) ^ cs) >> 1;

  f32x4 acc1[4][4], acc2[4][4];
  f32x4 zro = {0.f, 0.f, 0.f, 0.f};
#pragma unroll
  for (int i = 0; i < 4; ++i)
#pragma unroll
    for (int j = 0; j < 4; ++j) { acc1[i][j] = zro; acc2[i][j] = zro; }

  for (int cc = 0; cc < 36; ++cc) {
    int tap = cc >> 2, cq = cc & 3;
    int ty = tap / 3, tx = tap - ty * 3;
    int adel = (ty * W2 + tx) * 256 + (cq << 6);
    int bdel = (tap << 16) + (cq << 6);
    if (cc) __syncthreads();
#pragma unroll
    for (int i = 0; i < 4; ++i) {
      int d = i * 2048 + wv * 512;
      GLOAD16(xh + aoff[i] + adel, smem + d);
      GLOAD16(xl + aoff[i] + adel, smem + 8192 + d);
      GLOAD16(wh + boff[i] + bdel, smem + 16384 + d);
      GLOAD16(wl + boff[i] + bdel, smem + 24576 + d);
    }
    __syncthreads();
#pragma unroll
    for (int k2 = 0; k2 < 2; ++k2) {
      int ck = k2 ? c1 : c0;
      f16x8 ah[4], al[4], bh[4], bl[4];
#pragma unroll
      for (int q = 0; q < 4; ++q) {
        int ro = (rA0 + q * 16) * 64 + ck;
        ah[q] = *(const f16x8*)(smem + ro);
        al[q] = *(const f16x8*)(smem + 8192 + ro);
        int rb = (rB0 + q * 16) * 64 + ck;
        bh[q] = *(const f16x8*)(smem + 16384 + rb);
        bl[q] = *(const f16x8*)(smem + 24576 + rb);
      }
#pragma unroll
      for (int m4 = 0; m4 < 4; ++m4)
#pragma unroll
        for (int n4 = 0; n4 < 4; ++n4) {
          acc1[m4][n4] = __builtin_amdgcn_mfma_f32_16x16x32_f16(ah[m4], bh[n4], acc1[m4][n4], 0, 0, 0);
          acc2[m4][n4] = __builtin_amdgcn_mfma_f32_16x16x32_f16(ah[m4], bl[n4], acc2[m4][n4], 0, 0, 0);
          acc2[m4][n4] = __builtin_amdgcn_mfma_f32_16x16x32_f16(al[m4], bh[n4], acc2[m4][n4], 0, 0, 0);
        }
    }
  }

  float br[4];
#pragma unroll
  for (int n4 = 0; n4 < 4; ++n4) br[n4] = bias[co0 + wc * 64 + n4 * 16 + lr];
  float* outb = hbase + hoff + (size_t)b * HW * 256;
#pragma unroll
  for (int m4 = 0; m4 < 4; ++m4) {
#pragma unroll
    for (int j = 0; j < 4; ++j) {
      int pos = pos0 + wr * 64 + m4 * 16 + lk * 4 + j;
      if (pos < HW) {
        float* op = outb + (size_t)pos * 256 + co0 + wc * 64 + lr;
#pragma unroll
        for (int n4 = 0; n4 < 4; ++n4)
          op[n4 * 16] = acc1[m4][n4][j] + acc2[m4][n4][j] * 4.8828125e-4f + br[n4];
      }
    }
  }
}

// ---------------- heads v2: 4 threads/pixel, LDS-staged transposed weights, f32 VALU ----
__global__ __launch_bounds__(256) void head_kernel(
    const float* __restrict__ hbase, const float* __restrict__ loc_w, const float* __restrict__ loc_b,
    const float* __restrict__ score_w, const float* __restrict__ score_b,
    const float* __restrict__ anchors, const int* __restrict__ imgh, const int* __restrict__ imgw,
    float* __restrict__ out_locs, float* __restrict__ out_scores,
    float* __restrict__ boxes, u32* __restrict__ ukey)
{
  __shared__ float wT[4 * 1288];
  int tid = threadIdx.x;
  for (int idx = tid; idx < 4608; idx += 256) {          // 18*256
    int o = idx >> 8, c = idx & 255;
    float v = (o < 12) ? loc_w[o * 256 + c] : score_w[(o - 12) * 256 + c];
    wT[(c >> 6) * 1288 + (c & 63) * 20 + o] = v;
  }
  for (int idx = tid; idx < 512; idx += 256) {           // zero pad outputs 18,19
    int c = idx >> 1, o = 18 + (idx & 1);
    wT[(c >> 6) * 1288 + (c & 63) * 20 + o] = 0.f;
  }
  __syncthreads();

  int t = blockIdx.x;
  int b = t / 207, r = t % 207;
  int HW, pos0, base_row; size_t hoff;
  if (r < 157)      { HW = 10000; pos0 = r * 64;         base_row = 0;     hoff = 0; }
  else if (r < 197) { HW = 2500;  pos0 = (r - 157) * 64; base_row = 30000; hoff = 5120000; }
  else              { HW = 625;   pos0 = (r - 197) * 64; base_row = 37500; hoff = 6400000; }

  int px = tid >> 2, q = tid & 3;
  int pos = pos0 + px;
  int pc = (pos < HW) ? pos : HW - 1;
  const float* hp = hbase + hoff + ((size_t)b * HW + pc) * 256 + q * 64;
  const float* wq = wT + q * 1288;

  f32x4 acc[5];
#pragma unroll
  for (int o4 = 0; o4 < 5; ++o4) acc[o4] = (f32x4){0.f, 0.f, 0.f, 0.f};

#pragma unroll 4
  for (int i = 0; i < 16; ++i) {
    float4 hv = *(const float4*)(hp + i * 4);
    float hk[4] = {fmaxf(hv.x, 0.f), fmaxf(hv.y, 0.f), fmaxf(hv.z, 0.f), fmaxf(hv.w, 0.f)};
#pragma unroll
    for (int k = 0; k < 4; ++k) {
      const float4* wrow = (const float4*)(wq + (i * 4 + k) * 20);
#pragma unroll
      for (int o4 = 0; o4 < 5; ++o4) {
        float4 wv = wrow[o4];
        acc[o4][0] = fmaf(hk[k], wv.x, acc[o4][0]);
        acc[o4][1] = fmaf(hk[k], wv.y, acc[o4][1]);
        acc[o4][2] = fmaf(hk[k], wv.z, acc[o4][2]);
        acc[o4][3] = fmaf(hk[k], wv.w, acc[o4][3]);
      }
    }
  }
  // reduce over q (4-lane groups)
#pragma unroll
  for (int o4 = 0; o4 < 5; ++o4)
#pragma unroll
    for (int cpo = 0; cpo < 4; ++cpo) {
      float v = acc[o4][cpo];
      v += __shfl_xor(v, 1, 64);
      v += __shfl_xor(v, 2, 64);
      acc[o4][cpo] = v;
    }

  if (q == 0 && pos < HW) {
    float sarr[18] = {acc[0][0], acc[0][1], acc[0][2], acc[0][3],
                      acc[1][0], acc[1][1], acc[1][2], acc[1][3],
                      acc[2][0], acc[2][1], acc[2][2], acc[2][3],
                      acc[3][0], acc[3][1], acc[3][2], acc[3][3],
                      acc[4][0], acc[4][1]};
    float IH = (float)(*imgh), IW = (float)(*imgw);
#pragma unroll
    for (int a = 0; a < 3; ++a) {
      float l0 = sarr[4 * a + 0] + loc_b[4 * a + 0];
      float l1 = sarr[4 * a + 1] + loc_b[4 * a + 1];
      float l2 = sarr[4 * a + 2] + loc_b[4 * a + 2];
      float l3 = sarr[4 * a + 3] + loc_b[4 * a + 3];
      float sc0 = sarr[12 + 2 * a + 0] + score_b[2 * a + 0];
      float sc1 = sarr[12 + 2 * a + 1] + score_b[2 * a + 1];

      int row = base_row + pos * 3 + a;
      size_t g = (size_t)b * NANCHORS + row;
      *(float4*)(out_locs + g * 4) = make_float4(l0, l1, l2, l3);
      out_scores[g * 2 + 0] = sc0; out_scores[g * 2 + 1] = sc1;

      float mx = fmaxf(sc0, sc1);
      float e0 = expf(sc0 - mx), e1 = expf(sc1 - mx);
      float fg = e1 / (e0 + e1);

      const float* an = anchors + (size_t)row * 4;
      float a0 = an[0], a1 = an[1], a2 = an[2], a3 = an[3];
      float sh = a2 - a0, sw = a3 - a1;
      float cy = a0 + 0.5f * sh, cx = a1 + 0.5f * sw;
      float ncy = l0 * sh + cy, ncx = l1 * sw + cx;
      float nh = expf(l2) * sh, nw = expf(l3) * sw;
      float y1 = fminf(fmaxf(ncy - 0.5f * nh, 0.f), IH);
      float x1 = fminf(fmaxf(ncx - 0.5f * nw, 0.f), IW);
      float y2 = fminf(fmaxf(ncy + 0.5f * nh, 0.f), IH);
      float x2 = fminf(fmaxf(ncx + 0.5f * nw, 0.f), IW);
      bool valid = ((y2 - y1) >= 16.0f) && ((x2 - x1) >= 16.0f);
      float scm = valid ? fg : -__builtin_inff();

      *(float4*)(boxes + g * 4) = make_float4(y1, x1, y2, x2);
      ukey[g] = f2u(scm);
    }
  }
}

// ---------------- copy anchors to output ----------------
__global__ void copyf_kernel(const float* __restrict__ a, float* __restrict__ o, int n) {
  int t = blockIdx.x * 256 + threadIdx.x;
  if (t < n) o[t] = a[t];
}

// ---------------- merged radix-select + bitonic sort (same 2x1024 grid) -----------------
__global__ __launch_bounds__(1024) void selectsort_kernel(
    const u32* __restrict__ ukey, const float* __restrict__ boxes,
    float* __restrict__ topbox, u64* __restrict__ sup0)
{
  int b = blockIdx.x, tid = threadIdx.x;
  int wv = tid >> 6;
  const u32* u = ukey + (size_t)b * NANCHORS;
  __shared__ u32 hist[16][256];
  __shared__ u32 scan[256];
  __shared__ u32 sh_prefix;
  __shared__ int sh_rem;
  __shared__ int sh_cnt;
  __shared__ u64 key[CAND_CAP];
  __shared__ unsigned char validf[2048];

  u32 prefix = 0; int rem = PRE_NMS;
  for (int pass = 0; pass < 4; ++pass) {
    int shift = 24 - 8 * pass;
    for (int i = tid; i < 16 * 256; i += 1024) ((u32*)hist)[i] = 0;
    __syncthreads();
    u32 himask = (pass == 0) ? 0u : (0xFFFFFFFFu << (shift + 8));
    for (int i = tid; i < NANCHORS; i += 1024) {
      u32 v = u[i];
      if ((v & himask) == (prefix & himask))
        atomicAdd(&hist[wv][(v >> shift) & 255u], 1u);
    }
    __syncthreads();
    if (tid < 256) {
      u32 s = 0;
#pragma unroll
      for (int k = 0; k < 16; ++k) s += hist[k][tid];
      scan[tid] = s;
    }
    __syncthreads();
    for (int off = 1; off < 256; off <<= 1) {
      u32 v = 0, add = 0;
      if (tid < 256) { v = scan[tid]; if (tid + off < 256) add = scan[tid + off]; }
      __syncthreads();
      if (tid < 256) scan[tid] = v + add;
      __syncthreads();
    }
    if (tid < 256) {
      int s = (int)scan[tid];
      int snext = (tid < 255) ? (int)scan[tid + 1] : 0;
      if (s >= rem && snext < rem) { sh_prefix = prefix | ((u32)tid << shift); sh_rem = rem - snext; }
    }
    __syncthreads();
    prefix = sh_prefix; rem = sh_rem;
    __syncthreads();
  }

  if (tid == 0) sh_cnt = 0;
  __syncthreads();
  for (int i = tid; i < NANCHORS; i += 1024) {
    u32 v = u[i];
    if (v >= prefix) {
      int p = atomicAdd(&sh_cnt, 1);
      if (p < CAND_CAP)
        key[p] = ((u64)v << 32) | (u32)(~(u32)i);
    }
  }
  __syncthreads();
  int cnt = (sh_cnt < CAND_CAP) ? sh_cnt : CAND_CAP;
  for (int t = tid; t < CAND_CAP; t += 1024)
    if (t >= cnt) key[t] = 0ull;
  __syncthreads();

  u32 n = (cnt <= 2048) ? 2048u : (u32)CAND_CAP;
  for (u32 k = 2; k <= n; k <<= 1) {
    for (u32 j = k >> 1; j > 0; j >>= 1) {
      __syncthreads();
      for (u32 t = tid; t < n; t += 1024) {
        u32 ixj = t ^ j;
        if (ixj > t) {
          u64 a = key[t], c = key[ixj];
          bool desc = ((t & k) == 0);
          if (desc ? (a < c) : (a > c)) { key[t] = c; key[ixj] = a; }
        }
      }
    }
  }
  __syncthreads();

  for (int t = tid; t < 2048; t += 1024) {
    unsigned char vf = 0;
    if (t < PRE_NMS) {
      u64 kk = key[t];
      u32 uu = (u32)(kk >> 32);
      float* tb = topbox + ((size_t)b * PRE_NMS + t) * 4;
      if (uu != 0u) {
        u32 idx = ~((u32)kk);
        const float* bp = boxes + ((size_t)b * NANCHORS + idx) * 4;
        tb[0] = bp[0]; tb[1] = bp[1]; tb[2] = bp[2]; tb[3] = bp[3];
        vf = (uu != UNEG) ? 1 : 0;
      } else {
        tb[0] = 0.f; tb[1] = 0.f; tb[2] = 0.f; tb[3] = 0.f;
      }
    }
    validf[t] = vf;
  }
  __syncthreads();
  if (tid < 32) {
    u64 m = 0;
    for (int bit = 0; bit < 64; ++bit) {
      int j = tid * 64 + bit;
      if (j >= PRE_NMS || !validf[j]) m |= (1ull << bit);
    }
    sup0[b * 32 + tid] = m;
  }
}

// ---------------- pairwise IoU suppression bitmask, TRANSPOSED u32 layout ---------------
__global__ __launch_bounds__(256) void iou_kernel(const float* __restrict__ topbox, u32* __restrict__ M32)
{
  int t = blockIdx.x * 256 + threadIdx.x;   // < 64000
  int b = blockIdx.y;
  int w = t / 2000, i = t % 2000;
  const float* tb = topbox + (size_t)b * PRE_NMS * 4;
  const float* bi = tb + (size_t)i * 4;
  float iy1 = bi[0], ix1 = bi[1], iy2 = bi[2], ix2 = bi[3];
  float ai = (iy2 - iy1) * (ix2 - ix1);
  u64 m = 0;
  for (int bit = 0; bit < 64; ++bit) {
    int j = w * 64 + bit;
    if (j < PRE_NMS && j > i) {
      const float* bj = tb + (size_t)j * 4;
      float ty = fmaxf(iy1, bj[0]), tx = fmaxf(ix1, bj[1]);
      float by = fminf(iy2, bj[2]), bx = fminf(ix2, bj[3]);
      float hh = fmaxf(by - ty, 0.f), ww = fmaxf(bx - tx, 0.f);
      float inter = hh * ww;
      float aj = (bj[2] - bj[0]) * (bj[3] - bj[1]);
      float iou = inter / (ai + aj - inter + 1e-12f);
      if (iou > 0.7f) m |= (1ull << bit);
    }
  }
  u32* out = M32 + (size_t)b * MPAD * 64;
  out[(size_t)(2 * w)     * MPAD + i] = (u32)m;
  out[(size_t)(2 * w + 1) * MPAD + i] = (u32)(m >> 32);
}

// ---------------- merged NMS scan (1 wave, distributed regs) + emit top-300 -------------
__global__ __launch_bounds__(320) void final_kernel(
    const u32* __restrict__ M32, const u64* __restrict__ sup0, const float* __restrict__ topbox,
    float* __restrict__ rois, float* __restrict__ roiidx)
{
  int b = blockIdx.x, tid = threadIdx.x;
  __shared__ u32 supl[64];
  __shared__ int ord[POST_NMS];
  __shared__ int cnt_s;

  if (tid < 64) {
    int l = tid;                            // lane l owns u32 word l
    const u32* col = M32 + (size_t)b * MPAD * 64 + (size_t)l * MPAD;
    u32 sup = ((const u32*)sup0)[b * 64 + l];
    uint4 A[16], B[16];
#pragma unroll
    for (int k = 0; k < 16; ++k) A[k] = *(const uint4*)(col + 4 * k);

#define NMS_PROC(buf, cc) do {                                                     \
  _Pragma("unroll")                                                                \
  for (int rr = 0; rr < 64; ++rr) {                                                \
    u32 d = ((rr & 3) == 0) ? buf[rr >> 2].x : ((rr & 3) == 1) ? buf[rr >> 2].y :  \
            ((rr & 3) == 2) ? buf[rr >> 2].z : buf[rr >> 2].w;                     \
    u32 sb = (u32)__builtin_amdgcn_readlane((int)sup, 2 * (cc) + (rr >> 5));       \
    u32 m = ((sb >> (rr & 31)) & 1u) - 1u;                                         \
    sup |= m & d;                                                                  \
  } } while (0)

    for (int c = 0; c < 32; c += 2) {
#pragma unroll
      for (int k = 0; k < 16; ++k) B[k] = *(const uint4*)(col + (c + 1) * 64 + 4 * k);
      NMS_PROC(A, c);
      if (c + 2 < 32) {
#pragma unroll
        for (int k = 0; k < 16; ++k) A[k] = *(const uint4*)(col + (c + 2) * 64 + 4 * k);
      }
      NMS_PROC(B, c + 1);
    }
    supl[l] = sup;
  }
  __syncthreads();
  if (tid == 0) {
    int cnt = 0;
    for (int w = 0; w < 64 && cnt < POST_NMS; ++w) {
      u32 kept = ~supl[w];
      while (kept && cnt < POST_NMS) {
        int bit = __builtin_ctz(kept); kept &= kept - 1;
        ord[cnt++] = w * 32 + bit;
      }
    }
    cnt_s = cnt;
  }
  __syncthreads();
  if (tid < POST_NMS) {
    float v0 = 0.f, v1 = 0.f, v2 = 0.f, v3 = 0.f;
    if (tid < cnt_s) {
      const float* tb = topbox + ((size_t)b * PRE_NMS + ord[tid]) * 4;
      v0 = tb[0]; v1 = tb[1]; v2 = tb[2]; v3 = tb[3];
    }
    float* r = rois + ((size_t)b * POST_NMS + tid) * 4;
    r[0] = v0; r[1] = v1; r[2] = v2; r[3] = v3;
    roiidx[b * POST_NMS + tid] = (float)b;
  }
}

extern "C" void kernel_launch(void* const* d_in, const int* in_sizes, int n_in,
                              void* d_out, int out_size, void* d_ws, size_t ws_size,
                              hipStream_t stream) {
  const float* feat0   = (const float*)d_in[0];
  const float* feat1   = (const float*)d_in[1];
  const float* feat2   = (const float*)d_in[2];
  const float* conv_w  = (const float*)d_in[3];
  const float* conv_b  = (const float*)d_in[4];
  const float* score_w = (const float*)d_in[5];
  const float* score_b = (const float*)d_in[6];
  const float* loc_w   = (const float*)d_in[7];
  const float* loc_b   = (const float*)d_in[8];
  const float* anchors = (const float*)d_in[9];
  const int*   img_h   = (const int*)d_in[10];
  const int*   img_w   = (const int*)d_in[11];

  float* out_f       = (float*)d_out;
  float* out_locs    = out_f;                // 2*39375*4
  float* out_scores  = out_f + 315000;       // 2*39375*2
  float* out_rois    = out_f + 472500;       // 600*4
  float* out_roiidx  = out_f + 474900;       // 600
  float* out_anchors = out_f + 475500;       // 39375*4

  char* p = (char*)d_ws;
  float* hb = (float*)p;      p += (size_t)6720000 * 4;   // h = conv+bias (channels-last)
  short* xth = (short*)p;     p += (size_t)7084544 * 2;   // padded channels-last fp16 hi
  short* xtl = (short*)p;     p += (size_t)7084544 * 2;   // fp16 lo * 2^11
  short* wsh = (short*)p;     p += (size_t)589824 * 2;    // weights B^T [tap][co][ci] hi
  short* wsl = (short*)p;     p += (size_t)589824 * 2;    // lo * 2^11
  float* boxes = (float*)p;   p += (size_t)315000 * 4;    // 2*39375*4
  u32* ukey = (u32*)p;        p += (size_t)78752 * 4;     // 2*39375 (+2 pad: 16B align)
  float* topbox = (float*)p;  p += (size_t)16000 * 4;     // 2*2000*4
  u32* M32 = (u32*)p;         p += (size_t)2 * MPAD * 64 * 4;  // transposed mask
  u64* sup0 = (u64*)p;        p += 64 * 8;

  // zero the spatial pad ring of xth+xtl (adjacent: one memset)
  hipMemsetAsync(xth, 0, (size_t)7084544 * 4, stream);
  xsplit_kernel<<<1656, 256, 0, stream>>>(feat0, feat1, feat2, xth, xtl);
  wsplit_kernel<<<2304, 256, 0, stream>>>(conv_w, wsh, wsl);
  gemmconv_kernel<<<416, 256, 0, stream>>>(xth, xtl, wsh, wsl, conv_b, hb);
  head_kernel<<<414, 256, 0, stream>>>(
      hb, loc_w, loc_b, score_w, score_b, anchors, img_h, img_w,
      out_locs, out_scores, boxes, ukey);
  copyf_kernel<<<(157500 + 255) / 256, 256, 0, stream>>>(anchors, out_anchors, 157500);
  selectsort_kernel<<<2, 1024, 0, stream>>>(ukey, boxes, topbox, sup0);
  iou_kernel<<<dim3(250, 2), 256, 0, stream>>>(topbox, M32);
  final_kernel<<<2, 320, 0, stream>>>(M32, sup0, topbox, out_rois, out_roiidx);
}

// Round 7
// 361.419 us; speedup vs baseline: 1.3431x; 1.0257x over previous
//
#include <hip/hip_runtime.h>
#include <hip/hip_fp16.h>
#include <cstdint>
#include <cstddef>

typedef unsigned long long u64;
typedef unsigned int u32;
typedef __attribute__((ext_vector_type(8))) _Float16 f16x8;
typedef __attribute__((ext_vector_type(4))) float f32x4;

#define NANCHORS 39375
#define PRE_NMS  2000
#define POST_NMS 300
#define CAND_CAP 4096
#define MPAD 2048          // padded row count of mask matrix
#define UNEG 0x007FFFFFu   // f2u(-inf)

__device__ __forceinline__ u32 f2u(float f) {
  u32 u = __float_as_uint(f);
  return (u & 0x80000000u) ? ~u : (u | 0x80000000u);
}

// async global->LDS, 16B per lane. LDS dest must be WAVE-UNIFORM base; HW adds lane*16.
#define GLOAD16(gp, lp) __builtin_amdgcn_global_load_lds( \
    (const __attribute__((address_space(1))) u32*)(const void*)(gp), \
    (__attribute__((address_space(3))) u32*)(void*)(lp), 16, 0, 0)

// ---------------- input split/transpose: NCHW f32 -> padded channels-last fp16 hi/lo ----
__global__ __launch_bounds__(256) void xsplit_kernel(
    const float* __restrict__ f0, const float* __restrict__ f1, const float* __restrict__ f2,
    short* __restrict__ xh, short* __restrict__ xl)
{
  __shared__ float tile[64][65];
  int t = blockIdx.x;
  int HW, W, W2, np; const float* fp; int AB, ABS;
  if (t < 1256)      { HW = 10000; W = 100; W2 = 102; np = 157; fp = f0; AB = 0;       ABS = 2663424; }
  else if (t < 1576) { t -= 1256; HW = 2500; W = 50; W2 = 52; np = 40; fp = f1; AB = 5326848; ABS = 692224; }
  else               { t -= 1576; HW = 625;  W = 25; W2 = 27; np = 10; fp = f2; AB = 6711296; ABS = 186624; }
  int posb = t % np, r = t / np;
  int ci0 = (r & 3) * 64, b = r >> 2;
  int pos0 = posb * 64;
  int tid = threadIdx.x, lane = tid & 63, w = tid >> 6;
  int rp = pos0 + lane; if (rp >= HW) rp = HW - 1;
  const float* src = fp + (size_t)(b * 256 + ci0) * HW;
#pragma unroll
  for (int p = 0; p < 16; ++p) {
    int cl = w * 16 + p;
    tile[cl][lane] = src[(size_t)cl * HW + rp];
  }
  __syncthreads();
  int pix = tid >> 2, cq = tid & 3;
  int pos = pos0 + pix;
  if (pos < HW) {
    int y = pos / W, x = pos - y * W;
    size_t ob = (size_t)AB + (size_t)b * ABS + ((size_t)((y + 1) * W2 + (x + 1))) * 256 + ci0 + cq * 16;
    __align__(16) short hs[16], ls[16];
#pragma unroll
    for (int j = 0; j < 16; ++j) {
      float v = tile[cq * 16 + j][pix];
      __half h = __float2half(v);
      __half l = __float2half((v - __half2float(h)) * 2048.0f);
      hs[j] = __half_as_short(h);
      ls[j] = __half_as_short(l);
    }
    *(int4*)(xh + ob) = ((int4*)hs)[0];
    *(int4*)(xh + ob + 8) = ((int4*)hs)[1];
    *(int4*)(xl + ob) = ((int4*)ls)[0];
    *(int4*)(xl + ob + 8) = ((int4*)ls)[1];
  }
}

// ---------------- weight split: [co][ci][tap] f32 -> B^T layout [tap][co][ci] fp16 hi/lo --
__global__ __launch_bounds__(256) void wsplit_kernel(
    const float* __restrict__ w, short* __restrict__ wh, short* __restrict__ wl)
{
  int idx = blockIdx.x * 256 + threadIdx.x;    // < 589824 = 9*256*256 exactly
  int tap = idx >> 16, co = (idx >> 8) & 255, ci = idx & 255;
  float v = w[(size_t)co * 2304 + ci * 9 + tap];
  __half h = __float2half(v);
  __half l = __float2half((v - __half2float(h)) * 2048.0f);
  wh[idx] = __half_as_short(h);
  wl[idx] = __half_as_short(l);
}

// ---------------- conv 3x3 as implicit-GEMM on MFMA (split-fp16, error-compensated) -----
// R4-proven version: 256 thr / 4 waves, 128x128 tile, A+B both LDS-staged (64KB), XOR
// swizzle both sides. LDS-read-pipe-bound at MfmaUtil ~45%. Do NOT replace LDS-A with
// direct-global A: lane-scattered 512B-stride gathers thrash L1 (R5: 206us, MfmaUtil 18%).
__global__ __launch_bounds__(256, 2) void gemmconv_kernel(
    const short* __restrict__ xh, const short* __restrict__ xl,
    const short* __restrict__ wh, const short* __restrict__ wl,
    const float* __restrict__ bias, float* __restrict__ hbase)
{
  __shared__ __align__(16) short smem[32768];  // Ah[128][64] | Al | Bh[128][64] | Bl

  int lb = (blockIdx.x & 7) * 52 + (blockIdx.x >> 3);
  int HW, W, W2, AB, ABS; size_t hoff;
  if (lb < 316)      { HW = 10000; W = 100; W2 = 102; AB = 0;       ABS = 2663424; hoff = 0; }
  else if (lb < 396) { lb -= 316; HW = 2500; W = 50; W2 = 52; AB = 5326848; ABS = 692224; hoff = 5120000; }
  else               { lb -= 396; HW = 625;  W = 25; W2 = 27; AB = 6711296; ABS = 186624; hoff = 6400000; }
  int mb = lb >> 2, b = (lb >> 1) & 1, nb = lb & 1;
  int pos0 = mb * 128, co0 = nb * 128;

  int tid = threadIdx.x;
  int s = tid & 7, mrow = tid >> 3;
  int aoff[4], boff[4];
#pragma unroll
  for (int i = 0; i < 4; ++i) {
    int m = i * 32 + mrow;
    int pos = pos0 + m; if (pos >= HW) pos = HW - 1;   // tail rows: clamp (store is masked)
    int y = pos / W, x = pos - y * W;
    aoff[i] = AB + b * ABS + (y * W2 + x) * 256 + ((s ^ (m & 7)) << 3);
    boff[i] = ((co0 + m) << 8) + ((s ^ (m & 7)) << 3);
  }
  int wv = tid >> 6, lane = tid & 63;
  int lr = lane & 15, lk = lane >> 4;
  int wr = wv >> 1, wc = wv & 1;
  int rA0 = wr * 64 + lr, rB0 = wc * 64 + lr;
  int cs = (lr & 7) << 4;
  int c0 = ((lk * 16) ^ cs) >> 1;
  int c1 = ((64 + lk * 16) ^ cs) >> 1;

  f32x4 acc1[4][4], acc2[4][4];
  f32x4 zro = {0.f, 0.f, 0.f, 0.f};
#pragma unroll
  for (int i = 0; i < 4; ++i)
#pragma unroll
    for (int j = 0; j < 4; ++j) { acc1[i][j] = zro; acc2[i][j] = zro; }

  for (int cc = 0; cc < 36; ++cc) {
    int tap = cc >> 2, cq = cc & 3;
    int ty = tap / 3, tx = tap - ty * 3;
    int adel = (ty * W2 + tx) * 256 + (cq << 6);
    int bdel = (tap << 16) + (cq << 6);
    if (cc) __syncthreads();
#pragma unroll
    for (int i = 0; i < 4; ++i) {
      int d = i * 2048 + wv * 512;
      GLOAD16(xh + aoff[i] + adel, smem + d);
      GLOAD16(xl + aoff[i] + adel, smem + 8192 + d);
      GLOAD16(wh + boff[i] + bdel, smem + 16384 + d);
      GLOAD16(wl + boff[i] + bdel, smem + 24576 + d);
    }
    __syncthreads();
#pragma unroll
    for (int k2 = 0; k2 < 2; ++k2) {
      int ck = k2 ? c1 : c0;
      f16x8 ah[4], al[4], bh[4], bl[4];
#pragma unroll
      for (int q = 0; q < 4; ++q) {
        int ro = (rA0 + q * 16) * 64 + ck;
        ah[q] = *(const f16x8*)(smem + ro);
        al[q] = *(const f16x8*)(smem + 8192 + ro);
        int rb = (rB0 + q * 16) * 64 + ck;
        bh[q] = *(const f16x8*)(smem + 16384 + rb);
        bl[q] = *(const f16x8*)(smem + 24576 + rb);
      }
#pragma unroll
      for (int m4 = 0; m4 < 4; ++m4)
#pragma unroll
        for (int n4 = 0; n4 < 4; ++n4) {
          acc1[m4][n4] = __builtin_amdgcn_mfma_f32_16x16x32_f16(ah[m4], bh[n4], acc1[m4][n4], 0, 0, 0);
          acc2[m4][n4] = __builtin_amdgcn_mfma_f32_16x16x32_f16(ah[m4], bl[n4], acc2[m4][n4], 0, 0, 0);
          acc2[m4][n4] = __builtin_amdgcn_mfma_f32_16x16x32_f16(al[m4], bh[n4], acc2[m4][n4], 0, 0, 0);
        }
    }
  }

  float br[4];
#pragma unroll
  for (int n4 = 0; n4 < 4; ++n4) br[n4] = bias[co0 + wc * 64 + n4 * 16 + lr];
  float* outb = hbase + hoff + (size_t)b * HW * 256;
#pragma unroll
  for (int m4 = 0; m4 < 4; ++m4) {
#pragma unroll
    for (int j = 0; j < 4; ++j) {
      int pos = pos0 + wr * 64 + m4 * 16 + lk * 4 + j;
      if (pos < HW) {
        float* op = outb + (size_t)pos * 256 + co0 + wc * 64 + lr;
#pragma unroll
        for (int n4 = 0; n4 < 4; ++n4)
          op[n4 * 16] = acc1[m4][n4][j] + acc2[m4][n4][j] * 4.8828125e-4f + br[n4];
      }
    }
  }
}

// ---------------- heads v2: 4 threads/pixel, LDS-staged transposed weights, f32 VALU ----
__global__ __launch_bounds__(256) void head_kernel(
    const float* __restrict__ hbase, const float* __restrict__ loc_w, const float* __restrict__ loc_b,
    const float* __restrict__ score_w, const float* __restrict__ score_b,
    const float* __restrict__ anchors, const int* __restrict__ imgh, const int* __restrict__ imgw,
    float* __restrict__ out_locs, float* __restrict__ out_scores,
    float* __restrict__ boxes, u32* __restrict__ ukey)
{
  __shared__ float wT[4 * 1288];
  int tid = threadIdx.x;
  for (int idx = tid; idx < 4608; idx += 256) {          // 18*256
    int o = idx >> 8, c = idx & 255;
    float v = (o < 12) ? loc_w[o * 256 + c] : score_w[(o - 12) * 256 + c];
    wT[(c >> 6) * 1288 + (c & 63) * 20 + o] = v;
  }
  for (int idx = tid; idx < 512; idx += 256) {           // zero pad outputs 18,19
    int c = idx >> 1, o = 18 + (idx & 1);
    wT[(c >> 6) * 1288 + (c & 63) * 20 + o] = 0.f;
  }
  __syncthreads();

  int t = blockIdx.x;
  int b = t / 207, r = t % 207;
  int HW, pos0, base_row; size_t hoff;
  if (r < 157)      { HW = 10000; pos0 = r * 64;         base_row = 0;     hoff = 0; }
  else if (r < 197) { HW = 2500;  pos0 = (r - 157) * 64; base_row = 30000; hoff = 5120000; }
  else              { HW = 625;   pos0 = (r - 197) * 64; base_row = 37500; hoff = 6400000; }

  int px = tid >> 2, q = tid & 3;
  int pos = pos0 + px;
  int pc = (pos < HW) ? pos : HW - 1;
  const float* hp = hbase + hoff + ((size_t)b * HW + pc) * 256 + q * 64;
  const float* wq = wT + q * 1288;

  f32x4 acc[5];
#pragma unroll
  for (int o4 = 0; o4 < 5; ++o4) acc[o4] = (f32x4){0.f, 0.f, 0.f, 0.f};

#pragma unroll 4
  for (int i = 0; i < 16; ++i) {
    float4 hv = *(const float4*)(hp + i * 4);
    float hk[4] = {fmaxf(hv.x, 0.f), fmaxf(hv.y, 0.f), fmaxf(hv.z, 0.f), fmaxf(hv.w, 0.f)};
#pragma unroll
    for (int k = 0; k < 4; ++k) {
      const float4* wrow = (const float4*)(wq + (i * 4 + k) * 20);
#pragma unroll
      for (int o4 = 0; o4 < 5; ++o4) {
        float4 wv = wrow[o4];
        acc[o4][0] = fmaf(hk[k], wv.x, acc[o4][0]);
        acc[o4][1] = fmaf(hk[k], wv.y, acc[o4][1]);
        acc[o4][2] = fmaf(hk[k], wv.z, acc[o4][2]);
        acc[o4][3] = fmaf(hk[k], wv.w, acc[o4][3]);
      }
    }
  }
  // reduce over q (4-lane groups)
#pragma unroll
  for (int o4 = 0; o4 < 5; ++o4)
#pragma unroll
    for (int cpo = 0; cpo < 4; ++cpo) {
      float v = acc[o4][cpo];
      v += __shfl_xor(v, 1, 64);
      v += __shfl_xor(v, 2, 64);
      acc[o4][cpo] = v;
    }

  if (q == 0 && pos < HW) {
    float sarr[18] = {acc[0][0], acc[0][1], acc[0][2], acc[0][3],
                      acc[1][0], acc[1][1], acc[1][2], acc[1][3],
                      acc[2][0], acc[2][1], acc[2][2], acc[2][3],
                      acc[3][0], acc[3][1], acc[3][2], acc[3][3],
                      acc[4][0], acc[4][1]};
    float IH = (float)(*imgh), IW = (float)(*imgw);
#pragma unroll
    for (int a = 0; a < 3; ++a) {
      float l0 = sarr[4 * a + 0] + loc_b[4 * a + 0];
      float l1 = sarr[4 * a + 1] + loc_b[4 * a + 1];
      float l2 = sarr[4 * a + 2] + loc_b[4 * a + 2];
      float l3 = sarr[4 * a + 3] + loc_b[4 * a + 3];
      float sc0 = sarr[12 + 2 * a + 0] + score_b[2 * a + 0];
      float sc1 = sarr[12 + 2 * a + 1] + score_b[2 * a + 1];

      int row = base_row + pos * 3 + a;
      size_t g = (size_t)b * NANCHORS + row;
      *(float4*)(out_locs + g * 4) = make_float4(l0, l1, l2, l3);
      out_scores[g * 2 + 0] = sc0; out_scores[g * 2 + 1] = sc1;

      float mx = fmaxf(sc0, sc1);
      float e0 = expf(sc0 - mx), e1 = expf(sc1 - mx);
      float fg = e1 / (e0 + e1);

      const float* an = anchors + (size_t)row * 4;
      float a0 = an[0], a1 = an[1], a2 = an[2], a3 = an[3];
      float sh = a2 - a0, sw = a3 - a1;
      float cy = a0 + 0.5f * sh, cx = a1 + 0.5f * sw;
      float ncy = l0 * sh + cy, ncx = l1 * sw + cx;
      float nh = expf(l2) * sh, nw = expf(l3) * sw;
      float y1 = fminf(fmaxf(ncy - 0.5f * nh, 0.f), IH);
      float x1 = fminf(fmaxf(ncx - 0.5f * nw, 0.f), IW);
      float y2 = fminf(fmaxf(ncy + 0.5f * nh, 0.f), IH);
      float x2 = fminf(fmaxf(ncx + 0.5f * nw, 0.f), IW);
      bool valid = ((y2 - y1) >= 16.0f) && ((x2 - x1) >= 16.0f);
      float scm = valid ? fg : -__builtin_inff();

      *(float4*)(boxes + g * 4) = make_float4(y1, x1, y2, x2);
      ukey[g] = f2u(scm);
    }
  }
}

// ---------------- copy anchors to output ----------------
__global__ void copyf_kernel(const float* __restrict__ a, float* __restrict__ o, int n) {
  int t = blockIdx.x * 256 + threadIdx.x;
  if (t < n) o[t] = a[t];
}

// ---------------- merged radix-select + bitonic sort, v2 --------------------------------
// v2 (clustered-score aware): keys register-cached (39/thread, 1 global pass instead of 5);
// histogram uses readfirstlane+ballot majority-bin aggregation (1 atomic/wave/iter for
// clustered bins; stragglers individual = spread = conflict-free); 256-bin suffix-scan on
// wave0 via shfl (3 barriers/pass, not ~20); compact uses ballot-aggregated sh_cnt atomic.
// Order still exact: bitonic sorts by (score, ~idx).
__global__ __launch_bounds__(1024) void selectsort_kernel(
    const u32* __restrict__ ukey, const float* __restrict__ boxes,
    float* __restrict__ topbox, u64* __restrict__ sup0)
{
  int b = blockIdx.x, tid = threadIdx.x;
  int lane = tid & 63;
  const u32* u = ukey + (size_t)b * NANCHORS;
  __shared__ u32 hist[256];
  __shared__ u32 sh_prefix;
  __shared__ int sh_rem;
  __shared__ int sh_cnt;
  __shared__ u64 key[CAND_CAP];
  __shared__ unsigned char validf[2048];

  u32 val[39];                         // 39375 = 38*1024 + 463
#pragma unroll
  for (int k = 0; k < 38; ++k) val[k] = u[tid + k * 1024];
  val[38] = (tid < 463) ? u[tid + 38912] : 0u;

  u32 prefix = 0; int rem = PRE_NMS;
#pragma unroll 1
  for (int pass = 0; pass < 4; ++pass) {
    int shift = 24 - 8 * pass;
    if (tid < 256) hist[tid] = 0;
    __syncthreads();
    u32 himask = (pass == 0) ? 0u : (0xFFFFFFFFu << (shift + 8));
    u32 pmask = prefix & himask;
#pragma unroll
    for (int k = 0; k < 39; ++k) {
      bool live = (k < 38) || (tid < 463);
      u32 v = val[k];
      bool m = live && ((v & himask) == pmask);
      u32 bin = (v >> shift) & 255u;
      u64 actm = __ballot(m);
      if (actm) {
        int src = __ffsll(actm) - 1;
        u32 binf = __shfl(bin, src, 64);
        bool same = m && (bin == binf);
        u64 sm = __ballot(same);
        if (same) {
          if (lane == __ffsll(sm) - 1)
            atomicAdd(&hist[binf], (u32)__popcll(sm));
        } else if (m) {
          atomicAdd(&hist[bin], 1u);
        }
      }
    }
    __syncthreads();
    if (tid < 64) {
      u32 h0 = hist[4 * lane], h1 = hist[4 * lane + 1];
      u32 h2 = hist[4 * lane + 2], h3 = hist[4 * lane + 3];
      u32 L = h0 + h1 + h2 + h3;
      u32 SS = L;                      // inclusive suffix-sum across lanes
#pragma unroll
      for (int off = 1; off < 64; off <<= 1) {
        u32 tv = __shfl_down(SS, off, 64);
        if (lane + off < 64) SS += tv;
      }
      u32 T = SS - L;
      u32 s3 = h3 + T, s2 = h2 + s3, s1 = h1 + s2, s0 = h0 + s1;
      u32 sv[5] = {s0, s1, s2, s3, T};
#pragma unroll
      for (int j = 0; j < 4; ++j) {
        if ((int)sv[j] >= rem && (int)sv[j + 1] < rem) {   // unique crossing bin
          sh_prefix = prefix | ((u32)(4 * lane + j) << shift);
          sh_rem = rem - (int)sv[j + 1];
        }
      }
    }
    __syncthreads();
    prefix = sh_prefix; rem = sh_rem;
    // no barrier needed: next write of sh_prefix is 2 barriers away
  }

  if (tid == 0) sh_cnt = 0;
  __syncthreads();
#pragma unroll
  for (int k = 0; k < 39; ++k) {
    bool live = (k < 38) || (tid < 463);
    u32 v = val[k];
    bool c = live && (v >= prefix);
    u64 mask = __ballot(c);
    if (mask) {
      int leader = __ffsll(mask) - 1;
      int cntw = __popcll(mask);
      int base = 0;
      if (lane == leader) base = atomicAdd(&sh_cnt, cntw);
      base = __shfl(base, leader, 64);
      int p = base + (int)__popcll(mask & ((1ull << lane) - 1ull));
      if (c && p < CAND_CAP)
        key[p] = ((u64)v << 32) | (u32)(~(u32)(tid + k * 1024));
    }
  }
  __syncthreads();
  int cnt = (sh_cnt < CAND_CAP) ? sh_cnt : CAND_CAP;
  for (int t = tid; t < CAND_CAP; t += 1024)
    if (t >= cnt) key[t] = 0ull;
  __syncthreads();

  u32 n = (cnt <= 2048) ? 2048u : (u32)CAND_CAP;
  for (u32 k = 2; k <= n; k <<= 1) {
    for (u32 j = k >> 1; j > 0; j >>= 1) {
      __syncthreads();
      for (u32 t = tid; t < n; t += 1024) {
        u32 ixj = t ^ j;
        if (ixj > t) {
          u64 a = key[t], c = key[ixj];
          bool desc = ((t & k) == 0);
          if (desc ? (a < c) : (a > c)) { key[t] = c; key[ixj] = a; }
        }
      }
    }
  }
  __syncthreads();

  for (int t = tid; t < 2048; t += 1024) {
    unsigned char vf = 0;
    if (t < PRE_NMS) {
      u64 kk = key[t];
      u32 uu = (u32)(kk >> 32);
      float* tb = topbox + ((size_t)b * PRE_NMS + t) * 4;
      if (uu != 0u) {
        u32 idx = ~((u32)kk);
        const float* bp = boxes + ((size_t)b * NANCHORS + idx) * 4;
        tb[0] = bp[0]; tb[1] = bp[1]; tb[2] = bp[2]; tb[3] = bp[3];
        vf = (uu != UNEG) ? 1 : 0;
      } else {
        tb[0] = 0.f; tb[1] = 0.f; tb[2] = 0.f; tb[3] = 0.f;
      }
    }
    validf[t] = vf;
  }
  __syncthreads();
  if (tid < 32) {
    u64 m = 0;
    for (int bit = 0; bit < 64; ++bit) {
      int j = tid * 64 + bit;
      if (j >= PRE_NMS || !validf[j]) m |= (1ull << bit);
    }
    sup0[b * 32 + tid] = m;
  }
}

// ---------------- pairwise IoU suppression bitmask, TRANSPOSED u32 layout ---------------
__global__ __launch_bounds__(256) void iou_kernel(const float* __restrict__ topbox, u32* __restrict__ M32)
{
  int t = blockIdx.x * 256 + threadIdx.x;   // < 64000
  int b = blockIdx.y;
  int w = t / 2000, i = t % 2000;
  const float* tb = topbox + (size_t)b * PRE_NMS * 4;
  const float* bi = tb + (size_t)i * 4;
  float iy1 = bi[0], ix1 = bi[1], iy2 = bi[2], ix2 = bi[3];
  float ai = (iy2 - iy1) * (ix2 - ix1);
  u64 m = 0;
  for (int bit = 0; bit < 64; ++bit) {
    int j = w * 64 + bit;
    if (j < PRE_NMS && j > i) {
      const float* bj = tb + (size_t)j * 4;
      float ty = fmaxf(iy1, bj[0]), tx = fmaxf(ix1, bj[1]);
      float by = fminf(iy2, bj[2]), bx = fminf(ix2, bj[3]);
      float hh = fmaxf(by - ty, 0.f), ww = fmaxf(bx - tx, 0.f);
      float inter = hh * ww;
      float aj = (bj[2] - bj[0]) * (bj[3] - bj[1]);
      float iou = inter / (ai + aj - inter + 1e-12f);
      if (iou > 0.7f) m |= (1ull << bit);
    }
  }
  u32* out = M32 + (size_t)b * MPAD * 64;
  out[(size_t)(2 * w)     * MPAD + i] = (u32)m;
  out[(size_t)(2 * w + 1) * MPAD + i] = (u32)(m >> 32);
}

// ---------------- merged NMS scan (1 wave, distributed regs) + emit top-300 -------------
__global__ __launch_bounds__(320) void final_kernel(
    const u32* __restrict__ M32, const u64* __restrict__ sup0, const float* __restrict__ topbox,
    float* __restrict__ rois, float* __restrict__ roiidx)
{
  int b = blockIdx.x, tid = threadIdx.x;
  __shared__ u32 supl[64];
  __shared__ int ord[POST_NMS];
  __shared__ int cnt_s;

  if (tid < 64) {
    int l = tid;                            // lane l owns u32 word l
    const u32* col = M32 + (size_t)b * MPAD * 64 + (size_t)l * MPAD;
    u32 sup = ((const u32*)sup0)[b * 64 + l];
    uint4 A[16], B[16];
#pragma unroll
    for (int k = 0; k < 16; ++k) A[k] = *(const uint4*)(col + 4 * k);

#define NMS_PROC(buf, cc) do {                                                     \
  _Pragma("unroll")                                                                \
  for (int rr = 0; rr < 64; ++rr) {                                                \
    u32 d = ((rr & 3) == 0) ? buf[rr >> 2].x : ((rr & 3) == 1) ? buf[rr >> 2].y :  \
            ((rr & 3) == 2) ? buf[rr >> 2].z : buf[rr >> 2].w;                     \
    u32 sb = (u32)__builtin_amdgcn_readlane((int)sup, 2 * (cc) + (rr >> 5));       \
    u32 m = ((sb >> (rr & 31)) & 1u) - 1u;                                         \
    sup |= m & d;                                                                  \
  } } while (0)

    for (int c = 0; c < 32; c += 2) {
#pragma unroll
      for (int k = 0; k < 16; ++k) B[k] = *(const uint4*)(col + (c + 1) * 64 + 4 * k);
      NMS_PROC(A, c);
      if (c + 2 < 32) {
#pragma unroll
        for (int k = 0; k < 16; ++k) A[k] = *(const uint4*)(col + (c + 2) * 64 + 4 * k);
      }
      NMS_PROC(B, c + 1);
    }
    supl[l] = sup;
  }
  __syncthreads();
  if (tid == 0) {
    int cnt = 0;
    for (int w = 0; w < 64 && cnt < POST_NMS; ++w) {
      u32 kept = ~supl[w];
      while (kept && cnt < POST_NMS) {
        int bit = __builtin_ctz(kept); kept &= kept - 1;
        ord[cnt++] = w * 32 + bit;
      }
    }
    cnt_s = cnt;
  }
  __syncthreads();
  if (tid < POST_NMS) {
    float v0 = 0.f, v1 = 0.f, v2 = 0.f, v3 = 0.f;
    if (tid < cnt_s) {
      const float* tb = topbox + ((size_t)b * PRE_NMS + ord[tid]) * 4;
      v0 = tb[0]; v1 = tb[1]; v2 = tb[2]; v3 = tb[3];
    }
    float* r = rois + ((size_t)b * POST_NMS + tid) * 4;
    r[0] = v0; r[1] = v1; r[2] = v2; r[3] = v3;
    roiidx[b * POST_NMS + tid] = (float)b;
  }
}

extern "C" void kernel_launch(void* const* d_in, const int* in_sizes, int n_in,
                              void* d_out, int out_size, void* d_ws, size_t ws_size,
                              hipStream_t stream) {
  const float* feat0   = (const float*)d_in[0];
  const float* feat1   = (const float*)d_in[1];
  const float* feat2   = (const float*)d_in[2];
  const float* conv_w  = (const float*)d_in[3];
  const float* conv_b  = (const float*)d_in[4];
  const float* score_w = (const float*)d_in[5];
  const float* score_b = (const float*)d_in[6];
  const float* loc_w   = (const float*)d_in[7];
  const float* loc_b   = (const float*)d_in[8];
  const float* anchors = (const float*)d_in[9];
  const int*   img_h   = (const int*)d_in[10];
  const int*   img_w   = (const int*)d_in[11];

  float* out_f       = (float*)d_out;
  float* out_locs    = out_f;                // 2*39375*4
  float* out_scores  = out_f + 315000;       // 2*39375*2
  float* out_rois    = out_f + 472500;       // 600*4
  float* out_roiidx  = out_f + 474900;       // 600
  float* out_anchors = out_f + 475500;       // 39375*4

  char* p = (char*)d_ws;
  float* hb = (float*)p;      p += (size_t)6720000 * 4;   // h = conv+bias (channels-last)
  short* xth = (short*)p;     p += (size_t)7084544 * 2;   // padded channels-last fp16 hi
  short* xtl = (short*)p;     p += (size_t)7084544 * 2;   // fp16 lo * 2^11
  short* wsh = (short*)p;     p += (size_t)589824 * 2;    // weights B^T [tap][co][ci] hi
  short* wsl = (short*)p;     p += (size_t)589824 * 2;    // lo * 2^11
  float* boxes = (float*)p;   p += (size_t)315000 * 4;    // 2*39375*4
  u32* ukey = (u32*)p;        p += (size_t)78752 * 4;     // 2*39375 (+2 pad: 16B align)
  float* topbox = (float*)p;  p += (size_t)16000 * 4;     // 2*2000*4
  u32* M32 = (u32*)p;         p += (size_t)2 * MPAD * 64 * 4;  // transposed mask
  u64* sup0 = (u64*)p;        p += 64 * 8;

  // zero the spatial pad ring of xth+xtl (adjacent: one memset)
  hipMemsetAsync(xth, 0, (size_t)7084544 * 4, stream);
  xsplit_kernel<<<1656, 256, 0, stream>>>(feat0, feat1, feat2, xth, xtl);
  wsplit_kernel<<<2304, 256, 0, stream>>>(conv_w, wsh, wsl);
  gemmconv_kernel<<<416, 256, 0, stream>>>(xth, xtl, wsh, wsl, conv_b, hb);
  head_kernel<<<414, 256, 0, stream>>>(
      hb, loc_w, loc_b, score_w, score_b, anchors, img_h, img_w,
      out_locs, out_scores, boxes, ukey);
  copyf_kernel<<<(157500 + 255) / 256, 256, 0, stream>>>(anchors, out_anchors, 157500);
  selectsort_kernel<<<2, 1024, 0, stream>>>(ukey, boxes, topbox, sup0);
  iou_kernel<<<dim3(250, 2), 256, 0, stream>>>(topbox, M32);
  final_kernel<<<2, 320, 0, stream>>>(M32, sup0, topbox, out_rois, out_roiidx);
}